// Round 8
// baseline (414.002 us; speedup 1.0000x reference)
//
#include <hip/hip_runtime.h>
#include <math.h>

// ---------------------------------------------------------------------------
// PixelCNN (5 gated residual blocks) + DMOL logprob.  Round 12:
//   - NEW: k_blk trades ILP for TLP. 5-wave/1-row blocks (weight-once
//     partition: wave w = a-oc 32w..+31 + gate-oc 160+32w.. x 64 px),
//     SINGLE-buffered operands in a fully-unrolled 25-step loop (compiler
//     pipelines under the reg cap), __launch_bounds__(320,4) -> <=128 unified
//     regs -> 3 blocks = 15 waves/CU co-resident (LDS 3x46KB = 138KB).
//   - kept: bf16 residual stream + bf16 relu-mirror + global_load_lds staging
// ---------------------------------------------------------------------------

using short8  = __attribute__((ext_vector_type(8))) short;
using short4v = __attribute__((ext_vector_type(4))) short;
using f32x4   = __attribute__((ext_vector_type(4))) float;

static constexpr float L2E = 1.44269504088896f;   // log2(e)
static constexpr float LN2 = 0.69314718055995f;   // ln(2)

__device__ __forceinline__ float fexp2(float x) { return __builtin_amdgcn_exp2f(x); }
__device__ __forceinline__ float flog2(float x) { return __builtin_amdgcn_logf(x); }
__device__ __forceinline__ float frcp(float x)  { return __builtin_amdgcn_rcpf(x); }
__device__ __forceinline__ float fexp(float x)  { return fexp2(x * L2E); }
__device__ __forceinline__ float flog(float x)  { return flog2(x) * LN2; }
__device__ __forceinline__ float fsigmoid(float x) { return frcp(1.f + fexp2(-x * L2E)); }
__device__ __forceinline__ float ftanh(float x)    { return 1.f - 2.f * frcp(1.f + fexp2(x * (2.f * L2E))); }
__device__ __forceinline__ float fsoftplus(float z) {
    float e = fexp2(-fabsf(z) * L2E);
    return fmaxf(z, 0.f) + flog2(1.f + e) * LN2;
}

// pack two fp32 -> packed bf16 pair (a in low, b in high)
__device__ __forceinline__ unsigned pk_bf16(float a, float b) {
    union { float f; unsigned u; } ua, ub; ua.f = a; ub.f = b;
    return __builtin_amdgcn_perm(ub.u + 0x7fffu, ua.u + 0x7fffu, 0x07060302u);
}

__device__ __forceinline__ short f2bf(float f) {
    union { float f; unsigned u; } v; v.f = f;
    unsigned r = (v.u + 0x7fffu + ((v.u >> 16) & 1u)) >> 16;
    return (short)r;
}

__device__ __forceinline__ float bf2f(short s) {
    union { float f; unsigned u; } v;
    v.u = ((unsigned)(unsigned short)s) << 16;
    return v.f;
}

// async global->LDS DMA, 16B per lane; lds ptr must be wave-uniform
__device__ __forceinline__ void gload_lds16(const void* g, void* l) {
    __builtin_amdgcn_global_load_lds(
        (const __attribute__((address_space(1))) unsigned int*)g,
        (__attribute__((address_space(3))) unsigned int*)l, 16, 0, 0);
}

// workspace layout (bytes), 16B-aligned
static constexpr size_t X_OFF    = 0;             // 16*3*4096*4    = 786432
static constexpr size_t WINP_OFF = 786432;        // 3*160*32*2     = 30720
static constexpr size_t W1P_OFF  = 817152;        // 5*160*32*2     = 51200
static constexpr size_t W2P_OFF  = 868352;        // 5*160*32*2     = 51200
static constexpr size_t WPB_OFF  = 919552;        // 5*25*320*32*2  = 2560000
// bf16 residual stream h: [b][y][x][160], 16*4096*160*2 = 20971520 each
static constexpr size_t HRA_OFF  = 3479552;
static constexpr size_t HRB_OFF  = 24451072;
// bf16 relu-mirror: [b][row 0..64][x 0..65][168], row0 & x in {0,65} are zeros
// 16*65*66*168*2 = 23063040 B (+8192 slack for unconditional DMA over-read)
static constexpr size_t MA_OFF   = 45422592;
static constexpr size_t MB_OFF   = 68493824;      // end ~91.6 MB

static constexpr int MROWP = 66 * 168;            // mirror row pitch (shorts) = 11088

__global__ void k_prep(const float* __restrict__ s, float* __restrict__ x, int n) {
    int i = blockIdx.x * 256 + threadIdx.x;
    if (i < n) x[i] = 2.f * s[i] - 1.f;
}

// zero mirror borders: row 0 entirely, and x in {0,65} for rows 1..64; both mirrors
__global__ void k_mzero(short* __restrict__ MA, short* __restrict__ MB) {
    int idx = blockIdx.x * 256 + threadIdx.x;    // (mirror, b, cell 0..193, chunk 0..20)
    if (idx >= 2 * 16 * 194 * 21) return;
    int ch   = idx % 21;
    int cell = (idx / 21) % 194;
    int b    = (idx / (21 * 194)) % 16;
    short* M = (idx >= 16 * 194 * 21) ? MB : MA;
    int row, x;
    if (cell < 66) { row = 0; x = cell; }
    else { row = 1 + (cell - 66) / 2; x = ((cell - 66) & 1) ? 65 : 0; }
    short8 z = {};
    *(short8*)&M[((size_t)b * 65 + row) * MROWP + (size_t)x * 168 + ch * 8] = z;
}

// w_blk (5,320,160,3,3) -> bf16 wP[i][kt=tap*5+icb][oc320][icl32]
// one thread per (i,oc,ic): dense 36B read, coalesced short writes
__global__ void k_twb(const float* __restrict__ w, short* __restrict__ wP) {
    int idx = blockIdx.x * 256 + threadIdx.x;
    if (idx >= 5 * 320 * 160) return;
    int ic = idx % 160;
    int oc = (idx / 160) % 320;
    int i  = idx / (160 * 320);
    const float* p = w + (size_t)idx * 9;
    float t9[9];
    #pragma unroll
    for (int j = 0; j < 9; ++j) t9[j] = p[j];
    const int ky[5] = {0,0,0,1,1}, kx[5] = {0,1,2,0,1};
    #pragma unroll
    for (int tap = 0; tap < 5; ++tap)
        wP[(((size_t)i * 25 + tap * 5 + (ic >> 5)) * 320 + oc) * 32 + (ic & 31)] =
            f2bf(t9[ky[tap] * 3 + kx[tap]]);
}

// w_in (160,3,7,7) -> WINP[kc3][oc160][icl32], k=tap*3+ic over 24 mask-A taps, pad to 96
__global__ void k_twin(const float* __restrict__ w, short* __restrict__ wP) {
    int idx = blockIdx.x * 256 + threadIdx.x;
    if (idx >= 3 * 160 * 32) return;
    int icl = idx & 31;
    int oc  = (idx >> 5) % 160;
    int kc  = idx / 5120;
    int k = kc * 32 + icl;
    short v = 0;
    if (k < 72) {
        int tap = k / 3, ic = k % 3;
        int ky = (tap < 21) ? tap / 7 : 3;
        int kx = (tap < 21) ? tap % 7 : tap - 21;
        v = f2bf(w[((oc * 3 + ic) * 7 + ky) * 7 + kx]);
    }
    wP[idx] = v;
}

// w_out1 (160,160,1,1) -> W1P[kc5][oc160][icl32]
__global__ void k_tw1(const float* __restrict__ w, short* __restrict__ wP) {
    int idx = blockIdx.x * 256 + threadIdx.x;
    if (idx >= 5 * 160 * 32) return;
    int icl = idx & 31;
    int oc  = (idx >> 5) % 160;
    int kc  = idx / 5120;
    wP[idx] = f2bf(w[oc * 160 + kc * 32 + icl]);
}

// w_out2 (100,160,1,1) -> W2P[kc5][oc160 pad][icl32]
__global__ void k_tw2(const float* __restrict__ w, short* __restrict__ wP) {
    int idx = blockIdx.x * 256 + threadIdx.x;
    if (idx >= 5 * 160 * 32) return;
    int icl = idx & 31;
    int oc  = (idx >> 5) % 160;
    int kc  = idx / 5120;
    wP[idx] = (oc < 100) ? f2bf(w[oc * 160 + kc * 32 + icl]) : (short)0;
}

// masked 7x7 input conv, MFMA. grid (64,16) = (y,b), block 320 (5 waves).
// Writes h bf16 stream + bf16 relu mirror.
__global__ __launch_bounds__(320) void k_convin(const float* __restrict__ X,
                                                const short* __restrict__ WINP,
                                                short* __restrict__ hrout,
                                                short* __restrict__ Mout) {
    __shared__ float xls[3 * 4 * 72];   // [ic][r=ky][col], col = xg+3 (0..69)
    __shared__ short Bls[64 * 104];     // [px][k pad104]
    int y = blockIdx.x, b = blockIdx.y;
    int t = threadIdx.x;
    for (int i = t; i < 840; i += 320) {
        int col = i % 70; int r = (i / 70) % 4; int ic = i / 280;
        int xg = col - 3, yg = y + r - 3;
        float v = 0.f;
        if (xg >= 0 && xg < 64 && yg >= 0)
            v = X[((size_t)(b * 3 + ic) * 64 + yg) * 64 + xg];
        xls[(ic * 4 + r) * 72 + col] = v;
    }
    __syncthreads();
    for (int i = t; i < 6144; i += 320) {
        int k = i % 96; int px = i / 96;
        short v = 0;
        if (k < 72) {
            int tap = k / 3, ic = k % 3;
            int ky = (tap < 21) ? tap / 7 : 3;
            int kx = (tap < 21) ? tap % 7 : tap - 21;
            v = f2bf(xls[(ic * 4 + ky) * 72 + px + kx]);
        }
        Bls[px * 104 + k] = v;
    }
    __syncthreads();
    int lane = t & 63, wv = t >> 6;
    int lx = lane & 15, q = lane >> 4;
    f32x4 acc[2][4] = {};
    const short* wl = WINP + lx * 32 + q * 8;
    #pragma unroll
    for (int kc = 0; kc < 3; ++kc) {
        short8 aF[2], bF[4];
        aF[0] = *(const short8*)(wl + (kc * 160 + 32 * wv) * 32);
        aF[1] = *(const short8*)(wl + (kc * 160 + 32 * wv + 16) * 32);
        #pragma unroll
        for (int nt = 0; nt < 4; ++nt)
            bF[nt] = *(const short8*)&Bls[(nt * 16 + lx) * 104 + kc * 32 + q * 8];
        #pragma unroll
        for (int mt = 0; mt < 2; ++mt)
            #pragma unroll
            for (int nt = 0; nt < 4; ++nt)
                acc[mt][nt] = __builtin_amdgcn_mfma_f32_16x16x32_bf16(
                    aF[mt], bF[nt], acc[mt][nt], 0, 0, 0);
    }
    size_t rowbase = ((size_t)(b * 64 + y)) * 64 * 160;
    short* mrow = Mout + ((size_t)b * 65 + y + 1) * MROWP;
    #pragma unroll
    for (int mt = 0; mt < 2; ++mt) {
        int c0 = 32 * wv + mt * 16 + q * 4;
        #pragma unroll
        for (int nt = 0; nt < 4; ++nt) {
            int px = nt * 16 + lx;
            float4 o;
            o.x = acc[mt][nt][0]; o.y = acc[mt][nt][1];
            o.z = acc[mt][nt][2]; o.w = acc[mt][nt][3];
            union { short4v s; unsigned u[2]; } hv, mv;
            hv.u[0] = pk_bf16(o.x, o.y);
            hv.u[1] = pk_bf16(o.z, o.w);
            mv.u[0] = pk_bf16(fmaxf(o.x, 0.f), fmaxf(o.y, 0.f));
            mv.u[1] = pk_bf16(fmaxf(o.z, 0.f), fmaxf(o.w, 0.f));
            *(short4v*)&hrout[rowbase + (size_t)px * 160 + c0] = hv.s;
            *(short4v*)&mrow[(size_t)(px + 1) * 168 + c0] = mv.s;
        }
    }
}

// MFMA gated block conv. grid (64,16) = (y,b), block 320 (5 waves), TLP-first:
// 3 blocks/CU (LDS 46KB, <=128 unified regs via launch_bounds(320,4)).
// Wave w owns a-oc 32w..32w+31 and gate-oc 160+32w.. (weights read once per
// block). Single-buffered operands, fully unrolled: compiler pipelines.
__global__ __launch_bounds__(320, 4) void k_blk(const short* __restrict__ hin,
                                                const short* __restrict__ Min,
                                                short* __restrict__ hout,
                                                short* __restrict__ Mout,
                                                const short* __restrict__ wP) {
    __shared__ short in_s[2880 * 8];   // 46080 B; first 44352 = [r][x 0..65][168]
    int y = blockIdx.x, b = blockIdx.y;
    int t = threadIdx.x;
    int wv = t >> 6;
    int lane = t & 63;
    int lx = lane & 15, q = lane >> 4;
    size_t rowbase = ((size_t)(b * 64 + y)) * 64 * 160;

    // mirror rows y, y+1 == h rows y-1, y (row 0 is the zero row)
    const short* src = Min + ((size_t)b * 65 + y) * MROWP;
    #pragma unroll
    for (int k = 0; k < 9; ++k)
        gload_lds16(src + ((size_t)k * 320 + t) * 8, &in_s[(k * 320 + wv * 64) * 8]);
    __syncthreads();

    f32x4 acc[4][4] = {};
    const short* wl = wP + lx * 32 + q * 8;
    const int dxs[5] = {-1, 0, 1, -1, 0};
    const int rws[5] = {0, 0, 0, 1, 1};
    #pragma unroll
    for (int kk = 0; kk < 25; ++kk) {
        int tap = kk / 5, k5 = kk % 5;
        const short* wk = wl + kk * 10240;
        short8 aF[4], bF[4];
        aF[0] = *(const short8*)(wk + (32 * wv) * 32);
        aF[1] = *(const short8*)(wk + (32 * wv + 16) * 32);
        aF[2] = *(const short8*)(wk + (160 + 32 * wv) * 32);
        aF[3] = *(const short8*)(wk + (176 + 32 * wv) * 32);
        int rb = (rws[tap] * 66 + 1 + dxs[tap] + lx) * 168 + q * 8 + k5 * 32;
        #pragma unroll
        for (int nt = 0; nt < 4; ++nt)
            bF[nt] = *(const short8*)&in_s[rb + nt * 16 * 168];
        __builtin_amdgcn_s_setprio(1);
        #pragma unroll
        for (int mt = 0; mt < 4; ++mt)
            #pragma unroll
            for (int nt = 0; nt < 4; ++nt)
                acc[mt][nt] = __builtin_amdgcn_mfma_f32_16x16x32_bf16(
                    aF[mt], bF[nt], acc[mt][nt], 0, 0, 0);
        __builtin_amdgcn_s_setprio(0);
    }
    // epilogue: gating + residual rmw (bf16 stream) + bf16 relu-mirror write
    short* mrow = Mout + ((size_t)b * 65 + y + 1) * MROWP;
    #pragma unroll
    for (int mt = 0; mt < 2; ++mt) {
        int c0 = 32 * wv + mt * 16 + q * 4;
        #pragma unroll
        for (int nt = 0; nt < 4; ++nt) {
            int px = nt * 16 + lx;
            size_t off = rowbase + (size_t)px * 160 + c0;
            short4v hp = *(const short4v*)&hin[off];
            float4 o;
            o.x = bf2f(hp.x) + ftanh(acc[mt][nt][0]) * fsigmoid(acc[mt + 2][nt][0]);
            o.y = bf2f(hp.y) + ftanh(acc[mt][nt][1]) * fsigmoid(acc[mt + 2][nt][1]);
            o.z = bf2f(hp.z) + ftanh(acc[mt][nt][2]) * fsigmoid(acc[mt + 2][nt][2]);
            o.w = bf2f(hp.w) + ftanh(acc[mt][nt][3]) * fsigmoid(acc[mt + 2][nt][3]);
            union { short4v s; unsigned u[2]; } hv, mv;
            hv.u[0] = pk_bf16(o.x, o.y);
            hv.u[1] = pk_bf16(o.z, o.w);
            mv.u[0] = pk_bf16(fmaxf(o.x, 0.f), fmaxf(o.y, 0.f));
            mv.u[1] = pk_bf16(fmaxf(o.z, 0.f), fmaxf(o.w, 0.f));
            *(short4v*)&hout[off] = hv.s;
            *(short4v*)&mrow[(size_t)(px + 1) * 168 + c0] = mv.s;
        }
    }
}

// fused head: (mirror already holds relu(h) bf16) -> conv1x1(W1) -> relu ->
// conv1x1(W2) -> DMOL -> atomicAdd.  grid (64,16) = (y,b), block 320 (5 waves).
__global__ __launch_bounds__(320) void k_head(const short* __restrict__ Min,
                                              const short* __restrict__ W1P,
                                              const short* __restrict__ W2P,
                                              const float* __restrict__ X,
                                              float* __restrict__ out) {
    __shared__ __align__(16) char arenaA[29696]; // hls(21504) then Pls(26624)+lpls(3072)
    __shared__ short h2ls[64 * 168];             // 21504 B
    short* hls = (short*)arenaA;                 // [px][ic pad168] bf16 relu(h)
    float* Pls = (float*)arenaA;                 // [px][c pad104] fp32 params
    float* lpls = (float*)(arenaA + 26624);      // [px][m pad12]
    int y = blockIdx.x, b = blockIdx.y;
    int t = threadIdx.x;
    int wv = t >> 6;
    // stage relu(h) bf16 straight from mirror (x=1..64 of mirror row y+1)
    const short* src = Min + ((size_t)b * 65 + y + 1) * MROWP + 168;
    #pragma unroll
    for (int k = 0; k < 5; ++k)
        gload_lds16(src + ((size_t)k * 320 + t) * 8, &hls[(k * 320 + wv * 64) * 8]);
    __syncthreads();
    int lane = t & 63;
    int lx = lane & 15, q = lane >> 4;
    // GEMM1: h2 = relu(W1 * relu(h))
    {
        f32x4 acc[2][4] = {};
        const short* wl = W1P + lx * 32 + q * 8;
        #pragma unroll
        for (int kc = 0; kc < 5; ++kc) {
            short8 aF[2], bF[4];
            aF[0] = *(const short8*)(wl + (kc * 160 + 32 * wv) * 32);
            aF[1] = *(const short8*)(wl + (kc * 160 + 32 * wv + 16) * 32);
            #pragma unroll
            for (int nt = 0; nt < 4; ++nt)
                bF[nt] = *(const short8*)&hls[(nt * 16 + lx) * 168 + kc * 32 + q * 8];
            #pragma unroll
            for (int mt = 0; mt < 2; ++mt)
                #pragma unroll
                for (int nt = 0; nt < 4; ++nt)
                    acc[mt][nt] = __builtin_amdgcn_mfma_f32_16x16x32_bf16(
                        aF[mt], bF[nt], acc[mt][nt], 0, 0, 0);
        }
        #pragma unroll
        for (int mt = 0; mt < 2; ++mt) {
            int c0 = 32 * wv + mt * 16 + q * 4;
            #pragma unroll
            for (int nt = 0; nt < 4; ++nt) {
                int px = nt * 16 + lx;
                union { short4v s; unsigned u[2]; } sv;
                sv.u[0] = pk_bf16(fmaxf(acc[mt][nt][0], 0.f), fmaxf(acc[mt][nt][1], 0.f));
                sv.u[1] = pk_bf16(fmaxf(acc[mt][nt][2], 0.f), fmaxf(acc[mt][nt][3], 0.f));
                *(short4v*)&h2ls[px * 168 + c0] = sv.s;
            }
        }
    }
    __syncthreads();
    // GEMM2: params = W2 * h2   (oc padded to 160; only c<100 stored)
    {
        f32x4 acc[2][4] = {};
        const short* wl = W2P + lx * 32 + q * 8;
        #pragma unroll
        for (int kc = 0; kc < 5; ++kc) {
            short8 aF[2], bF[4];
            aF[0] = *(const short8*)(wl + (kc * 160 + 32 * wv) * 32);
            aF[1] = *(const short8*)(wl + (kc * 160 + 32 * wv + 16) * 32);
            #pragma unroll
            for (int nt = 0; nt < 4; ++nt)
                bF[nt] = *(const short8*)&h2ls[(nt * 16 + lx) * 168 + kc * 32 + q * 8];
            #pragma unroll
            for (int mt = 0; mt < 2; ++mt)
                #pragma unroll
                for (int nt = 0; nt < 4; ++nt)
                    acc[mt][nt] = __builtin_amdgcn_mfma_f32_16x16x32_bf16(
                        aF[mt], bF[nt], acc[mt][nt], 0, 0, 0);
        }
        #pragma unroll
        for (int mt = 0; mt < 2; ++mt) {
            int c0 = 32 * wv + mt * 16 + q * 4;
            if (c0 < 100) {
                #pragma unroll
                for (int nt = 0; nt < 4; ++nt) {
                    int px = nt * 16 + lx;
                    float4 o;
                    o.x = acc[mt][nt][0]; o.y = acc[mt][nt][1];
                    o.z = acc[mt][nt][2]; o.w = acc[mt][nt][3];
                    *(float4*)&Pls[px * 104 + c0] = o;
                }
            }
        }
    }
    __syncthreads();
    // DMOL: 640 (px, mixture) tasks over 320 threads
    const float LOG127P5 = 4.8481163504f;   // ln(127.5)
    #pragma unroll
    for (int it = 0; it < 2; ++it) {
        int tk = t + it * 320;
        int px = tk & 63, m = tk >> 6;
        const float* pp = &Pls[px * 104];
        float xs[3];
        #pragma unroll
        for (int c = 0; c < 3; ++c)
            xs[c] = X[((size_t)(b * 3 + c)) * 4096 + (size_t)y * 64 + px];
        float mx = pp[0];
        #pragma unroll
        for (int j = 1; j < 10; ++j) mx = fmaxf(mx, pp[j]);
        float se = 0.f;
        #pragma unroll
        for (int j = 0; j < 10; ++j) se += fexp(pp[j] - mx);
        float lse = mx + flog(se);
        float sum = pp[m] - lse;
        float mean0 = pp[10 + m];
        float mean1 = pp[40 + m];
        float mean2 = pp[70 + m];
        float ls0 = fmaxf(pp[20 + m], -7.f);
        float ls1 = fmaxf(pp[50 + m], -7.f);
        float ls2 = fmaxf(pp[80 + m], -7.f);
        float c0 = ftanh(pp[30 + m]);
        float c1 = ftanh(pp[60 + m]);
        float c2 = ftanh(pp[90 + m]);
        float mu[3], lsv[3];
        mu[0] = mean0;
        mu[1] = mean1 + c0 * xs[0];
        mu[2] = mean2 + c1 * xs[0] + c2 * xs[1];
        lsv[0] = ls0; lsv[1] = ls1; lsv[2] = ls2;
        #pragma unroll
        for (int ci = 0; ci < 3; ++ci) {
            float cent = xs[ci] - mu[ci];
            float inv = fexp(-lsv[ci]);
            float plus_in = inv * (cent + 1.f / 255.f);
            float min_in = inv * (cent - 1.f / 255.f);
            float cdf_delta = fsigmoid(plus_in) - fsigmoid(min_in);
            float log_cdf_plus = plus_in - fsoftplus(plus_in);
            float log_om_cdf = -fsoftplus(min_in);
            float mid = inv * cent;
            float log_pdf_mid = mid - lsv[ci] - 2.f * fsoftplus(mid);
            float lpi = (cdf_delta > 1e-5f) ? flog(fmaxf(cdf_delta, 1e-12f))
                                            : (log_pdf_mid - LOG127P5);
            float lpc = (xs[ci] < -0.999f) ? log_cdf_plus
                       : ((xs[ci] > 0.999f) ? log_om_cdf : lpi);
            sum += lpc;
        }
        lpls[px * 12 + m] = sum;
    }
    __syncthreads();
    if (t < 64) {
        int px = t;
        float mx2 = lpls[px * 12];
        #pragma unroll
        for (int m = 1; m < 10; ++m) mx2 = fmaxf(mx2, lpls[px * 12 + m]);
        float se2 = 0.f;
        #pragma unroll
        for (int m = 0; m < 10; ++m) se2 += fexp(lpls[px * 12 + m] - mx2);
        float lp = mx2 + flog(se2);
        #pragma unroll
        for (int off = 32; off > 0; off >>= 1) lp += __shfl_down(lp, off, 64);
        if (t == 0) atomicAdd(&out[b], lp);
    }
}

extern "C" void kernel_launch(void* const* d_in, const int* in_sizes, int n_in,
                              void* d_out, int out_size, void* d_ws, size_t ws_size,
                              hipStream_t stream) {
    const float* samples = (const float*)d_in[0];
    const float* w_in    = (const float*)d_in[1];
    const float* w_blk   = (const float*)d_in[2];
    const float* w_out1  = (const float*)d_in[3];
    const float* w_out2  = (const float*)d_in[4];
    char* ws = (char*)d_ws;
    float* X    = (float*)(ws + X_OFF);
    short* WINP = (short*)(ws + WINP_OFF);
    short* W1P  = (short*)(ws + W1P_OFF);
    short* W2P  = (short*)(ws + W2P_OFF);
    short* WPB  = (short*)(ws + WPB_OFF);
    short* HRA  = (short*)(ws + HRA_OFF);
    short* HRB  = (short*)(ws + HRB_OFF);
    short* MA   = (short*)(ws + MA_OFF);
    short* MB   = (short*)(ws + MB_OFF);
    float* fout = (float*)d_out;

    k_prep<<<768, 256, 0, stream>>>(samples, X, 16 * 3 * 4096);
    k_mzero<<<510, 256, 0, stream>>>(MA, MB);
    k_twb<<<1000, 256, 0, stream>>>(w_blk, WPB);
    k_twin<<<60, 256, 0, stream>>>(w_in, WINP);
    k_tw1<<<100, 256, 0, stream>>>(w_out1, W1P);
    k_tw2<<<100, 256, 0, stream>>>(w_out2, W2P);

    k_convin<<<dim3(64, 16), 320, 0, stream>>>(X, WINP, HRA, MA);

    short* a = HRA; short* bq = HRB;
    short* ma = MA; short* mb = MB;
    for (int i = 0; i < 5; i++) {
        k_blk<<<dim3(64, 16), 320, 0, stream>>>(a, ma, bq, mb,
                                                WPB + (size_t)i * 25 * 320 * 32);
        short* tf = a; a = bq; bq = tf;
        short* tm = ma; ma = mb; mb = tm;
    }
    // final h mirror is in ma (= MB after 5 swaps)
    hipMemsetAsync(d_out, 0, (size_t)out_size * sizeof(float), stream);
    k_head<<<dim3(64, 16), 320, 0, stream>>>(ma, W1P, W2P, X, fout);
}

// Round 9
// 296.723 us; speedup vs baseline: 1.3952x; 1.3952x over previous
//
#include <hip/hip_runtime.h>
#include <math.h>

// ---------------------------------------------------------------------------
// PixelCNN (5 gated residual blocks) + DMOL logprob.  Round 13:
//   - k_blk = round-11 structure (best measured: 43.7 us/layer) with the
//     weight pipeline deepened to 3 buffers (2 loads/step, kk+3 refill).
//   - NEW: all 6 small prep kernels merged into one k_setup launch.
//   - NEW: final k_blk layer skips the dead h-stream write (runtime flag).
//   - kept: bf16 residual stream + bf16 relu-mirror + global_load_lds staging
// ---------------------------------------------------------------------------

using short8  = __attribute__((ext_vector_type(8))) short;
using short4v = __attribute__((ext_vector_type(4))) short;
using f32x4   = __attribute__((ext_vector_type(4))) float;

static constexpr float L2E = 1.44269504088896f;   // log2(e)
static constexpr float LN2 = 0.69314718055995f;   // ln(2)

__device__ __forceinline__ float fexp2(float x) { return __builtin_amdgcn_exp2f(x); }
__device__ __forceinline__ float flog2(float x) { return __builtin_amdgcn_logf(x); }
__device__ __forceinline__ float frcp(float x)  { return __builtin_amdgcn_rcpf(x); }
__device__ __forceinline__ float fexp(float x)  { return fexp2(x * L2E); }
__device__ __forceinline__ float flog(float x)  { return flog2(x) * LN2; }
__device__ __forceinline__ float fsigmoid(float x) { return frcp(1.f + fexp2(-x * L2E)); }
__device__ __forceinline__ float ftanh(float x)    { return 1.f - 2.f * frcp(1.f + fexp2(x * (2.f * L2E))); }
__device__ __forceinline__ float fsoftplus(float z) {
    float e = fexp2(-fabsf(z) * L2E);
    return fmaxf(z, 0.f) + flog2(1.f + e) * LN2;
}

// pack two fp32 -> packed bf16 pair (a in low, b in high)
__device__ __forceinline__ unsigned pk_bf16(float a, float b) {
    union { float f; unsigned u; } ua, ub; ua.f = a; ub.f = b;
    return __builtin_amdgcn_perm(ub.u + 0x7fffu, ua.u + 0x7fffu, 0x07060302u);
}

__device__ __forceinline__ short f2bf(float f) {
    union { float f; unsigned u; } v; v.f = f;
    unsigned r = (v.u + 0x7fffu + ((v.u >> 16) & 1u)) >> 16;
    return (short)r;
}

__device__ __forceinline__ float bf2f(short s) {
    union { float f; unsigned u; } v;
    v.u = ((unsigned)(unsigned short)s) << 16;
    return v.f;
}

// async global->LDS DMA, 16B per lane; lds ptr must be wave-uniform
__device__ __forceinline__ void gload_lds16(const void* g, void* l) {
    __builtin_amdgcn_global_load_lds(
        (const __attribute__((address_space(1))) unsigned int*)g,
        (__attribute__((address_space(3))) unsigned int*)l, 16, 0, 0);
}

// workspace layout (bytes), 16B-aligned
static constexpr size_t X_OFF    = 0;             // 16*3*4096*4    = 786432
static constexpr size_t WINP_OFF = 786432;        // 3*160*32*2     = 30720
static constexpr size_t W1P_OFF  = 817152;        // 5*160*32*2     = 51200
static constexpr size_t W2P_OFF  = 868352;        // 5*160*32*2     = 51200
static constexpr size_t WPB_OFF  = 919552;        // 5*25*320*32*2  = 2560000
// bf16 residual stream h: [b][y][x][160], 16*4096*160*2 = 20971520 each
static constexpr size_t HRA_OFF  = 3479552;
static constexpr size_t HRB_OFF  = 24451072;
// bf16 relu-mirror: [b][row 0..64][x 0..65][168], row0 & x in {0,65} are zeros
// 16*65*66*168*2 = 23063040 B (+8192 slack for unconditional DMA over-read)
static constexpr size_t MA_OFF   = 45422592;
static constexpr size_t MB_OFF   = 68493824;      // end ~91.6 MB

static constexpr int MROWP = 66 * 168;            // mirror row pitch (shorts) = 11088
static constexpr int SLOT  = 11264;               // staging slot pitch (shorts) = 22528 B

// ---------------------------------------------------------------------------
// k_setup: all preprocessing in ONE launch.
//   blocks [0,768)      : X = 2*samples-1
//   blocks [768,1278)   : zero mirror borders (MA, MB)
//   blocks [1278,2278)  : w_blk  -> WPB
//   blocks [2278,2338)  : w_in   -> WINP
//   blocks [2338,2438)  : w_out1 -> W1P
//   blocks [2438,2538)  : w_out2 -> W2P
// ---------------------------------------------------------------------------
__global__ void k_setup(const float* __restrict__ s,
                        const float* __restrict__ w_in,
                        const float* __restrict__ w_blk,
                        const float* __restrict__ w_out1,
                        const float* __restrict__ w_out2,
                        float* __restrict__ X,
                        short* __restrict__ WINP,
                        short* __restrict__ WPB,
                        short* __restrict__ W1P,
                        short* __restrict__ W2P,
                        short* __restrict__ MA,
                        short* __restrict__ MB) {
    int bid = blockIdx.x;
    int t = threadIdx.x;
    if (bid < 768) {                       // ---- prep X
        int i = bid * 256 + t;
        if (i < 16 * 3 * 4096) X[i] = 2.f * s[i] - 1.f;
    } else if (bid < 1278) {               // ---- mirror border zero
        int idx = (bid - 768) * 256 + t;
        if (idx >= 2 * 16 * 194 * 21) return;
        int ch   = idx % 21;
        int cell = (idx / 21) % 194;
        int b    = (idx / (21 * 194)) % 16;
        short* M = (idx >= 16 * 194 * 21) ? MB : MA;
        int row, x;
        if (cell < 66) { row = 0; x = cell; }
        else { row = 1 + (cell - 66) / 2; x = ((cell - 66) & 1) ? 65 : 0; }
        short8 z = {};
        *(short8*)&M[((size_t)b * 65 + row) * MROWP + (size_t)x * 168 + ch * 8] = z;
    } else if (bid < 2278) {               // ---- w_blk transform
        int idx = (bid - 1278) * 256 + t;
        if (idx >= 5 * 320 * 160) return;
        int ic = idx % 160;
        int oc = (idx / 160) % 320;
        int i  = idx / (160 * 320);
        const float* p = w_blk + (size_t)idx * 9;
        float t9[9];
        #pragma unroll
        for (int j = 0; j < 9; ++j) t9[j] = p[j];
        const int ky[5] = {0,0,0,1,1}, kx[5] = {0,1,2,0,1};
        #pragma unroll
        for (int tap = 0; tap < 5; ++tap)
            WPB[(((size_t)i * 25 + tap * 5 + (ic >> 5)) * 320 + oc) * 32 + (ic & 31)] =
                f2bf(t9[ky[tap] * 3 + kx[tap]]);
    } else if (bid < 2338) {               // ---- w_in transform
        int idx = (bid - 2278) * 256 + t;
        if (idx >= 3 * 160 * 32) return;
        int icl = idx & 31;
        int oc  = (idx >> 5) % 160;
        int kc  = idx / 5120;
        int k = kc * 32 + icl;
        short v = 0;
        if (k < 72) {
            int tap = k / 3, ic = k % 3;
            int ky = (tap < 21) ? tap / 7 : 3;
            int kx = (tap < 21) ? tap % 7 : tap - 21;
            v = f2bf(w_in[((oc * 3 + ic) * 7 + ky) * 7 + kx]);
        }
        WINP[idx] = v;
    } else if (bid < 2438) {               // ---- w_out1 transform
        int idx = (bid - 2338) * 256 + t;
        if (idx >= 5 * 160 * 32) return;
        int icl = idx & 31;
        int oc  = (idx >> 5) % 160;
        int kc  = idx / 5120;
        W1P[idx] = f2bf(w_out1[oc * 160 + kc * 32 + icl]);
    } else {                               // ---- w_out2 transform
        int idx = (bid - 2438) * 256 + t;
        if (idx >= 5 * 160 * 32) return;
        int icl = idx & 31;
        int oc  = (idx >> 5) % 160;
        int kc  = idx / 5120;
        W2P[idx] = (oc < 100) ? f2bf(w_out2[oc * 160 + kc * 32 + icl]) : (short)0;
    }
}

// masked 7x7 input conv, MFMA. grid (64,16) = (y,b), block 320 (5 waves).
// Writes h bf16 stream + bf16 relu mirror.
__global__ __launch_bounds__(320) void k_convin(const float* __restrict__ X,
                                                const short* __restrict__ WINP,
                                                short* __restrict__ hrout,
                                                short* __restrict__ Mout) {
    __shared__ float xls[3 * 4 * 72];   // [ic][r=ky][col], col = xg+3 (0..69)
    __shared__ short Bls[64 * 104];     // [px][k pad104]
    int y = blockIdx.x, b = blockIdx.y;
    int t = threadIdx.x;
    for (int i = t; i < 840; i += 320) {
        int col = i % 70; int r = (i / 70) % 4; int ic = i / 280;
        int xg = col - 3, yg = y + r - 3;
        float v = 0.f;
        if (xg >= 0 && xg < 64 && yg >= 0)
            v = X[((size_t)(b * 3 + ic) * 64 + yg) * 64 + xg];
        xls[(ic * 4 + r) * 72 + col] = v;
    }
    __syncthreads();
    for (int i = t; i < 6144; i += 320) {
        int k = i % 96; int px = i / 96;
        short v = 0;
        if (k < 72) {
            int tap = k / 3, ic = k % 3;
            int ky = (tap < 21) ? tap / 7 : 3;
            int kx = (tap < 21) ? tap % 7 : tap - 21;
            v = f2bf(xls[(ic * 4 + ky) * 72 + px + kx]);
        }
        Bls[px * 104 + k] = v;
    }
    __syncthreads();
    int lane = t & 63, wv = t >> 6;
    int lx = lane & 15, q = lane >> 4;
    f32x4 acc[2][4] = {};
    const short* wl = WINP + lx * 32 + q * 8;
    #pragma unroll
    for (int kc = 0; kc < 3; ++kc) {
        short8 aF[2], bF[4];
        aF[0] = *(const short8*)(wl + (kc * 160 + 32 * wv) * 32);
        aF[1] = *(const short8*)(wl + (kc * 160 + 32 * wv + 16) * 32);
        #pragma unroll
        for (int nt = 0; nt < 4; ++nt)
            bF[nt] = *(const short8*)&Bls[(nt * 16 + lx) * 104 + kc * 32 + q * 8];
        #pragma unroll
        for (int mt = 0; mt < 2; ++mt)
            #pragma unroll
            for (int nt = 0; nt < 4; ++nt)
                acc[mt][nt] = __builtin_amdgcn_mfma_f32_16x16x32_bf16(
                    aF[mt], bF[nt], acc[mt][nt], 0, 0, 0);
    }
    size_t rowbase = ((size_t)(b * 64 + y)) * 64 * 160;
    short* mrow = Mout + ((size_t)b * 65 + y + 1) * MROWP;
    #pragma unroll
    for (int mt = 0; mt < 2; ++mt) {
        int c0 = 32 * wv + mt * 16 + q * 4;
        #pragma unroll
        for (int nt = 0; nt < 4; ++nt) {
            int px = nt * 16 + lx;
            float4 o;
            o.x = acc[mt][nt][0]; o.y = acc[mt][nt][1];
            o.z = acc[mt][nt][2]; o.w = acc[mt][nt][3];
            union { short4v s; unsigned u[2]; } hv, mv;
            hv.u[0] = pk_bf16(o.x, o.y);
            hv.u[1] = pk_bf16(o.z, o.w);
            mv.u[0] = pk_bf16(fmaxf(o.x, 0.f), fmaxf(o.y, 0.f));
            mv.u[1] = pk_bf16(fmaxf(o.z, 0.f), fmaxf(o.w, 0.f));
            *(short4v*)&hrout[rowbase + (size_t)px * 160 + c0] = hv.s;
            *(short4v*)&mrow[(size_t)(px + 1) * 168 + c0] = mv.s;
        }
    }
}

// MFMA gated block conv. grid (32,16) = (y-pair,b), block 640 (10 waves).
// Wave w owns a-channels 16w..16w+15 and gate-channels 160+16w.. for ALL
// 128 px (rows y0,y0+1). Weights read once per block, 3-deep register
// pipeline (2 loads/step). B: 8 ds_read_b128/step, 1-ahead dbuf.
__global__ __launch_bounds__(640, 3) void k_blk(const short* __restrict__ hin,
                                                const short* __restrict__ Min,
                                                short* __restrict__ hout,
                                                short* __restrict__ Mout,
                                                const short* __restrict__ wP,
                                                int writeH) {
    __shared__ short in_s[3 * SLOT];   // 3 x 22528 B = 67584 B
    int b = blockIdx.y;
    int y0 = blockIdx.x * 2;
    int t = threadIdx.x;
    int w = t >> 6;               // 0..9 (oc-slice)
    int lane = t & 63;
    int lx = lane & 15, q = lane >> 4;

    // stage mirror rows y0..y0+2 into slots 0..2 (22 chunks x 1024 B per slot)
    #pragma unroll
    for (int m = 0; m < 3; ++m) {
        const short* src = Min + ((size_t)b * 65 + y0 + m) * MROWP;
        #pragma unroll
        for (int k = 0; k < 3; ++k) {
            int ch = k * 10 + w;
            if (ch < 22)
                gload_lds16(src + (size_t)(ch * 64 + lane) * 8, &in_s[m * SLOT + ch * 512]);
        }
    }

    f32x4 acc[2][8] = {};
    const short* wl = wP + lx * 32 + q * 8;
    const int dxs[5] = {-1, 0, 1, -1, 0};
    const int rws[5] = {0, 0, 0, 1, 1};

    short8 aF[3][2], bF[2][8];
    // 3-deep weight prologue: a-tile (oc 16w) + gate-tile (oc 160+16w)
    #pragma unroll
    for (int p = 0; p < 3; ++p) {
        const short* wk = wl + p * 10240;
        aF[p][0] = *(const short8*)(wk + (16 * w) * 32);
        aF[p][1] = *(const short8*)(wk + (160 + 16 * w) * 32);
    }
    __syncthreads();   // staging DMA complete (weights also drained here)

    // B-fragments for step 0 (tap0: rws=0, dxs=-1): tiles 0-3 slot0, 4-7 slot1
    {
        int rb = lx * 168 + q * 8;
        #pragma unroll
        for (int nt = 0; nt < 4; ++nt) {
            bF[0][nt]     = *(const short8*)&in_s[rb + nt * 16 * 168];
            bF[0][nt + 4] = *(const short8*)&in_s[SLOT + rb + nt * 16 * 168];
        }
    }
    #pragma unroll
    for (int kk = 0; kk < 25; ++kk) {
        // 1-ahead B prefetch (LDS): 8 fragments (4 px-tiles x 2 rows)
        if (kk < 24) {
            int kn = kk + 1, tap = kn / 5, k5 = kn % 5;
            int base0 = rws[tap] ? SLOT : 0;
            int base1 = rws[tap] ? 2 * SLOT : SLOT;
            int rb = (1 + dxs[tap] + lx) * 168 + q * 8 + k5 * 32;
            #pragma unroll
            for (int nt = 0; nt < 4; ++nt) {
                bF[kn & 1][nt]     = *(const short8*)&in_s[base0 + rb + nt * 16 * 168];
                bF[kn & 1][nt + 4] = *(const short8*)&in_s[base1 + rb + nt * 16 * 168];
            }
        }
        __builtin_amdgcn_s_setprio(1);
        #pragma unroll
        for (int mt = 0; mt < 2; ++mt)
            #pragma unroll
            for (int nt = 0; nt < 8; ++nt)
                acc[mt][nt] = __builtin_amdgcn_mfma_f32_16x16x32_bf16(
                    aF[kk % 3][mt], bF[kk & 1][nt], acc[mt][nt], 0, 0, 0);
        __builtin_amdgcn_s_setprio(0);
        // 3-ahead weight refill into the buffer just consumed
        if (kk + 3 < 25) {
            const short* wk = wl + (kk + 3) * 10240;
            aF[kk % 3][0] = *(const short8*)(wk + (16 * w) * 32);
            aF[kk % 3][1] = *(const short8*)(wk + (160 + 16 * w) * 32);
        }
    }
    // epilogue: gating + residual rmw (bf16 stream) + bf16 relu-mirror write
    int c0 = 16 * w + q * 4;
    #pragma unroll
    for (int r = 0; r < 2; ++r) {
        int y = y0 + r;
        size_t rowbase = ((size_t)(b * 64 + y)) * 64 * 160;
        short* mrow = Mout + ((size_t)b * 65 + y + 1) * MROWP;
        #pragma unroll
        for (int nt = 0; nt < 4; ++nt) {
            int idx = r * 4 + nt;
            int px = nt * 16 + lx;
            size_t off = rowbase + (size_t)px * 160 + c0;
            short4v hp = *(const short4v*)&hin[off];
            float4 o;
            o.x = bf2f(hp.x) + ftanh(acc[0][idx][0]) * fsigmoid(acc[1][idx][0]);
            o.y = bf2f(hp.y) + ftanh(acc[0][idx][1]) * fsigmoid(acc[1][idx][1]);
            o.z = bf2f(hp.z) + ftanh(acc[0][idx][2]) * fsigmoid(acc[1][idx][2]);
            o.w = bf2f(hp.w) + ftanh(acc[0][idx][3]) * fsigmoid(acc[1][idx][3]);
            union { short4v s; unsigned u[2]; } hv, mv;
            hv.u[0] = pk_bf16(o.x, o.y);
            hv.u[1] = pk_bf16(o.z, o.w);
            mv.u[0] = pk_bf16(fmaxf(o.x, 0.f), fmaxf(o.y, 0.f));
            mv.u[1] = pk_bf16(fmaxf(o.z, 0.f), fmaxf(o.w, 0.f));
            if (writeH) *(short4v*)&hout[off] = hv.s;
            *(short4v*)&mrow[(size_t)(px + 1) * 168 + c0] = mv.s;
        }
    }
}

// fused head: (mirror already holds relu(h) bf16) -> conv1x1(W1) -> relu ->
// conv1x1(W2) -> DMOL -> atomicAdd.  grid (64,16) = (y,b), block 320 (5 waves).
__global__ __launch_bounds__(320) void k_head(const short* __restrict__ Min,
                                              const short* __restrict__ W1P,
                                              const short* __restrict__ W2P,
                                              const float* __restrict__ X,
                                              float* __restrict__ out) {
    __shared__ __align__(16) char arenaA[29696]; // hls(21504) then Pls(26624)+lpls(3072)
    __shared__ short h2ls[64 * 168];             // 21504 B
    short* hls = (short*)arenaA;                 // [px][ic pad168] bf16 relu(h)
    float* Pls = (float*)arenaA;                 // [px][c pad104] fp32 params
    float* lpls = (float*)(arenaA + 26624);      // [px][m pad12]
    int y = blockIdx.x, b = blockIdx.y;
    int t = threadIdx.x;
    int wv = t >> 6;
    // stage relu(h) bf16 straight from mirror (x=1..64 of mirror row y+1)
    const short* src = Min + ((size_t)b * 65 + y + 1) * MROWP + 168;
    #pragma unroll
    for (int k = 0; k < 5; ++k)
        gload_lds16(src + ((size_t)k * 320 + t) * 8, &hls[(k * 320 + wv * 64) * 8]);
    __syncthreads();
    int lane = t & 63;
    int lx = lane & 15, q = lane >> 4;
    // GEMM1: h2 = relu(W1 * relu(h))
    {
        f32x4 acc[2][4] = {};
        const short* wl = W1P + lx * 32 + q * 8;
        #pragma unroll
        for (int kc = 0; kc < 5; ++kc) {
            short8 aF[2], bF[4];
            aF[0] = *(const short8*)(wl + (kc * 160 + 32 * wv) * 32);
            aF[1] = *(const short8*)(wl + (kc * 160 + 32 * wv + 16) * 32);
            #pragma unroll
            for (int nt = 0; nt < 4; ++nt)
                bF[nt] = *(const short8*)&hls[(nt * 16 + lx) * 168 + kc * 32 + q * 8];
            #pragma unroll
            for (int mt = 0; mt < 2; ++mt)
                #pragma unroll
                for (int nt = 0; nt < 4; ++nt)
                    acc[mt][nt] = __builtin_amdgcn_mfma_f32_16x16x32_bf16(
                        aF[mt], bF[nt], acc[mt][nt], 0, 0, 0);
        }
        #pragma unroll
        for (int mt = 0; mt < 2; ++mt) {
            int c0 = 32 * wv + mt * 16 + q * 4;
            #pragma unroll
            for (int nt = 0; nt < 4; ++nt) {
                int px = nt * 16 + lx;
                union { short4v s; unsigned u[2]; } sv;
                sv.u[0] = pk_bf16(fmaxf(acc[mt][nt][0], 0.f), fmaxf(acc[mt][nt][1], 0.f));
                sv.u[1] = pk_bf16(fmaxf(acc[mt][nt][2], 0.f), fmaxf(acc[mt][nt][3], 0.f));
                *(short4v*)&h2ls[px * 168 + c0] = sv.s;
            }
        }
    }
    __syncthreads();
    // GEMM2: params = W2 * h2   (oc padded to 160; only c<100 stored)
    {
        f32x4 acc[2][4] = {};
        const short* wl = W2P + lx * 32 + q * 8;
        #pragma unroll
        for (int kc = 0; kc < 5; ++kc) {
            short8 aF[2], bF[4];
            aF[0] = *(const short8*)(wl + (kc * 160 + 32 * wv) * 32);
            aF[1] = *(const short8*)(wl + (kc * 160 + 32 * wv + 16) * 32);
            #pragma unroll
            for (int nt = 0; nt < 4; ++nt)
                bF[nt] = *(const short8*)&h2ls[(nt * 16 + lx) * 168 + kc * 32 + q * 8];
            #pragma unroll
            for (int mt = 0; mt < 2; ++mt)
                #pragma unroll
                for (int nt = 0; nt < 4; ++nt)
                    acc[mt][nt] = __builtin_amdgcn_mfma_f32_16x16x32_bf16(
                        aF[mt], bF[nt], acc[mt][nt], 0, 0, 0);
        }
        #pragma unroll
        for (int mt = 0; mt < 2; ++mt) {
            int c0 = 32 * wv + mt * 16 + q * 4;
            if (c0 < 100) {
                #pragma unroll
                for (int nt = 0; nt < 4; ++nt) {
                    int px = nt * 16 + lx;
                    float4 o;
                    o.x = acc[mt][nt][0]; o.y = acc[mt][nt][1];
                    o.z = acc[mt][nt][2]; o.w = acc[mt][nt][3];
                    *(float4*)&Pls[px * 104 + c0] = o;
                }
            }
        }
    }
    __syncthreads();
    // DMOL: 640 (px, mixture) tasks over 320 threads
    const float LOG127P5 = 4.8481163504f;   // ln(127.5)
    #pragma unroll
    for (int it = 0; it < 2; ++it) {
        int tk = t + it * 320;
        int px = tk & 63, m = tk >> 6;
        const float* pp = &Pls[px * 104];
        float xs[3];
        #pragma unroll
        for (int c = 0; c < 3; ++c)
            xs[c] = X[((size_t)(b * 3 + c)) * 4096 + (size_t)y * 64 + px];
        float mx = pp[0];
        #pragma unroll
        for (int j = 1; j < 10; ++j) mx = fmaxf(mx, pp[j]);
        float se = 0.f;
        #pragma unroll
        for (int j = 0; j < 10; ++j) se += fexp(pp[j] - mx);
        float lse = mx + flog(se);
        float sum = pp[m] - lse;
        float mean0 = pp[10 + m];
        float mean1 = pp[40 + m];
        float mean2 = pp[70 + m];
        float ls0 = fmaxf(pp[20 + m], -7.f);
        float ls1 = fmaxf(pp[50 + m], -7.f);
        float ls2 = fmaxf(pp[80 + m], -7.f);
        float c0 = ftanh(pp[30 + m]);
        float c1 = ftanh(pp[60 + m]);
        float c2 = ftanh(pp[90 + m]);
        float mu[3], lsv[3];
        mu[0] = mean0;
        mu[1] = mean1 + c0 * xs[0];
        mu[2] = mean2 + c1 * xs[0] + c2 * xs[1];
        lsv[0] = ls0; lsv[1] = ls1; lsv[2] = ls2;
        #pragma unroll
        for (int ci = 0; ci < 3; ++ci) {
            float cent = xs[ci] - mu[ci];
            float inv = fexp(-lsv[ci]);
            float plus_in = inv * (cent + 1.f / 255.f);
            float min_in = inv * (cent - 1.f / 255.f);
            float cdf_delta = fsigmoid(plus_in) - fsigmoid(min_in);
            float log_cdf_plus = plus_in - fsoftplus(plus_in);
            float log_om_cdf = -fsoftplus(min_in);
            float mid = inv * cent;
            float log_pdf_mid = mid - lsv[ci] - 2.f * fsoftplus(mid);
            float lpi = (cdf_delta > 1e-5f) ? flog(fmaxf(cdf_delta, 1e-12f))
                                            : (log_pdf_mid - LOG127P5);
            float lpc = (xs[ci] < -0.999f) ? log_cdf_plus
                       : ((xs[ci] > 0.999f) ? log_om_cdf : lpi);
            sum += lpc;
        }
        lpls[px * 12 + m] = sum;
    }
    __syncthreads();
    if (t < 64) {
        int px = t;
        float mx2 = lpls[px * 12];
        #pragma unroll
        for (int m = 1; m < 10; ++m) mx2 = fmaxf(mx2, lpls[px * 12 + m]);
        float se2 = 0.f;
        #pragma unroll
        for (int m = 0; m < 10; ++m) se2 += fexp(lpls[px * 12 + m] - mx2);
        float lp = mx2 + flog(se2);
        #pragma unroll
        for (int off = 32; off > 0; off >>= 1) lp += __shfl_down(lp, off, 64);
        if (t == 0) atomicAdd(&out[b], lp);
    }
}

extern "C" void kernel_launch(void* const* d_in, const int* in_sizes, int n_in,
                              void* d_out, int out_size, void* d_ws, size_t ws_size,
                              hipStream_t stream) {
    const float* samples = (const float*)d_in[0];
    const float* w_in    = (const float*)d_in[1];
    const float* w_blk   = (const float*)d_in[2];
    const float* w_out1  = (const float*)d_in[3];
    const float* w_out2  = (const float*)d_in[4];
    char* ws = (char*)d_ws;
    float* X    = (float*)(ws + X_OFF);
    short* WINP = (short*)(ws + WINP_OFF);
    short* W1P  = (short*)(ws + W1P_OFF);
    short* W2P  = (short*)(ws + W2P_OFF);
    short* WPB  = (short*)(ws + WPB_OFF);
    short* HRA  = (short*)(ws + HRA_OFF);
    short* HRB  = (short*)(ws + HRB_OFF);
    short* MA   = (short*)(ws + MA_OFF);
    short* MB   = (short*)(ws + MB_OFF);
    float* fout = (float*)d_out;

    k_setup<<<2538, 256, 0, stream>>>(samples, w_in, w_blk, w_out1, w_out2,
                                      X, WINP, WPB, W1P, W2P, MA, MB);

    k_convin<<<dim3(64, 16), 320, 0, stream>>>(X, WINP, HRA, MA);

    short* a = HRA; short* bq = HRB;
    short* ma = MA; short* mb = MB;
    for (int i = 0; i < 5; i++) {
        k_blk<<<dim3(32, 16), 640, 0, stream>>>(a, ma, bq, mb,
                                                WPB + (size_t)i * 25 * 320 * 32,
                                                (i < 4) ? 1 : 0);
        short* tf = a; a = bq; bq = tf;
        short* tm = ma; ma = mb; mb = tm;
    }
    // final h mirror is in ma (= MB after 5 swaps)
    hipMemsetAsync(d_out, 0, (size_t)out_size * sizeof(float), stream);
    k_head<<<dim3(64, 16), 320, 0, stream>>>(ma, W1P, W2P, X, fout);
}